// Round 9
// baseline (327.277 us; speedup 1.0000x reference)
//
#include <hip/hip_runtime.h>
#include <hip/hip_fp16.h>

#define NN  25000
#define EE  500000
#define BB  4
#define DD  32
#define LL  4
#define R2C 474
#define BD  128      // B*D
#define THD 416      // 13*D
#define EPSF 1e-6f
#define WMH 13312    // halfs per layer of MFMA-packed W: 13 t * 2 nt * 64 * 8
#define CAP 64       // fixed CSR segment capacity (max degree ~45 for Poisson(20))
#define GBATCH 5     // generic-layer prefetch depth (slot groups of 4 edges)
#define L1BATCH 8    // layer1 prefetch depth

// merged build+setup grid partition
#define NEB    245   // ceil(EE/8 / 256), 8 edges/thread
#define NWMB   208   // LL*WMH / 256
#define NRELIN 948   // LL*R2C*BD / 256
#define NW1P   16    // 4096 / 256

typedef _Float16 half8 __attribute__((ext_vector_type(8)));
typedef _Float16 h2v   __attribute__((ext_vector_type(2)));
typedef float    f32x4 __attribute__((ext_vector_type(4)));

// packed fp16 max/min (no __hmax2/__hmin2 in ROCm's fp16 header)
__device__ __forceinline__ h2v h2max(h2v a, h2v b) {
  h2v d; asm("v_pk_max_f16 %0, %1, %2" : "=v"(d) : "v"(a), "v"(b)); return d;
}
__device__ __forceinline__ h2v h2min(h2v a, h2v b) {
  h2v d; asm("v_pk_min_f16 %0, %1, %2" : "=v"(d) : "v"(a), "v"(b)); return d;
}
__device__ __forceinline__ h2v shflx_h2(h2v v, int m) {
  union { h2v h; int i; } u; u.h = v;
  u.i = __shfl_xor(u.i, m);
  return u.h;
}
// f32 acc += f16(lo/hi of x) * onef  — single-instruction mixed fma
__device__ __forceinline__ float fmix_lo(float acc, h2v x, float onef) {
  asm("v_fma_mix_f32 %0, %1, %2, %0 op_sel:[0,0,0] op_sel_hi:[1,0,0]"
      : "+v"(acc) : "v"(x), "v"(onef));
  return acc;
}
__device__ __forceinline__ float fmix_hi(float acc, h2v x, float onef) {
  asm("v_fma_mix_f32 %0, %1, %2, %0 op_sel:[1,0,0] op_sel_hi:[1,0,0]"
      : "+v"(acc) : "v"(x), "v"(onef));
  return acc;
}
// f32 acc += f16(a) * f16(b) (lo/hi halves)
__device__ __forceinline__ float fmix2_lo(float acc, h2v a, h2v b) {
  asm("v_fma_mix_f32 %0, %1, %2, %0 op_sel:[0,0,0] op_sel_hi:[1,1,0]"
      : "+v"(acc) : "v"(a), "v"(b));
  return acc;
}
__device__ __forceinline__ float fmix2_hi(float acc, h2v a, h2v b) {
  asm("v_fma_mix_f32 %0, %1, %2, %0 op_sel:[1,1,0] op_sel_hi:[1,1,0]"
      : "+v"(acc) : "v"(a), "v"(b));
  return acc;
}

// ---------------- merged graph build + all query-side setup ----------------
__global__ __launch_bounds__(256) void build_setup_kernel(
    const int* __restrict__ node_in, const int* __restrict__ node_out,
    const int* __restrict__ relation, const float* __restrict__ ew,
    int* __restrict__ cnt, int2* __restrict__ ep,
    const float* __restrict__ linW, _Float16* __restrict__ Wm,
    const int* __restrict__ r_index, const float* __restrict__ qemb,
    const float* __restrict__ relW, const float* __restrict__ relB,
    __half* __restrict__ relIn, float* __restrict__ query,
    const float* __restrict__ W1, _Float16* __restrict__ W1m) {
  const int blk = blockIdx.x;
  const int tid = threadIdx.x;
  if (blk < NEB) {
    int i = blk * 256 + tid;                     // edge-octet index
    if (i >= EE / 8) return;
    const int4*   ni4 = (const int4*)node_in;
    const int4*   no4 = (const int4*)node_out;
    const int4*   rl4 = (const int4*)relation;
    const float4* ew4 = (const float4*)ew;
    int4   noA = no4[2 * i], noB = no4[2 * i + 1];
    int4   niA = ni4[2 * i], niB = ni4[2 * i + 1];
    int4   rlA = rl4[2 * i], rlB = rl4[2 * i + 1];
    float4 ewA = ew4[2 * i], ewB = ew4[2 * i + 1];
    int s0 = atomicAdd(&cnt[noA.x], 1);
    int s1 = atomicAdd(&cnt[noA.y], 1);
    int s2 = atomicAdd(&cnt[noA.z], 1);
    int s3 = atomicAdd(&cnt[noA.w], 1);
    int s4 = atomicAdd(&cnt[noB.x], 1);
    int s5 = atomicAdd(&cnt[noB.y], 1);
    int s6 = atomicAdd(&cnt[noB.z], 1);
    int s7 = atomicAdd(&cnt[noB.w], 1);
    ep[noA.x * CAP + s0] = make_int2(niA.x | (rlA.x << 15), __float_as_int(ewA.x));
    ep[noA.y * CAP + s1] = make_int2(niA.y | (rlA.y << 15), __float_as_int(ewA.y));
    ep[noA.z * CAP + s2] = make_int2(niA.z | (rlA.z << 15), __float_as_int(ewA.z));
    ep[noA.w * CAP + s3] = make_int2(niA.w | (rlA.w << 15), __float_as_int(ewA.w));
    ep[noB.x * CAP + s4] = make_int2(niB.x | (rlB.x << 15), __float_as_int(ewB.x));
    ep[noB.y * CAP + s5] = make_int2(niB.y | (rlB.y << 15), __float_as_int(ewB.y));
    ep[noB.z * CAP + s6] = make_int2(niB.z | (rlB.z << 15), __float_as_int(ewB.z));
    ep[noB.w * CAP + s7] = make_int2(niB.w | (rlB.w << 15), __float_as_int(ewB.w));
  } else if (blk < NEB + NWMB) {
    int idx = (blk - NEB) * 256 + tid;           // < LL*WMH exactly
    int l = idx / WMH, rest = idx % WMH;
    int t = rest >> 10;
    int nt = (rest >> 9) & 1;
    int L = (rest >> 3) & 63;
    int j = rest & 7;
    int k = t * 32 + (L >> 4) * 8 + j;
    int n = nt * 16 + (L & 15);
    int wrow;
    if (k < 32) wrow = k;
    else {
      int kk = k - 32;
      int slab = kk >> 7, s = (kk >> 5) & 3, dd = kk & 31;
      wrow = DD + (dd * 4 + s) * 3 + slab;
    }
    Wm[idx] = (_Float16)linW[(size_t)l * THD * DD + (size_t)wrow * DD + n];
  } else if (blk < NEB + NWMB + NRELIN) {
    int o = (blk - NEB - NWMB) * 256 + tid;      // < LL*R2C*BD exactly
    int l = o / (R2C * BD);
    int rest = o % (R2C * BD);
    int r = rest >> 7, b = (rest >> 5) & 3, d = rest & 31;
    int col = r * DD + d;
    const float* W = relW + (size_t)l * DD * R2C * DD;
    const float* qrow = qemb + (size_t)r_index[b] * DD;
    float acc = relB[(size_t)l * R2C * DD + col];
    #pragma unroll
    for (int k = 0; k < DD; ++k)
      acc = fmaf(qrow[k], W[(size_t)k * (R2C * DD) + col], acc);
    relIn[o] = __float2half(acc);
  } else if (blk < NEB + NWMB + NRELIN + NW1P) {
    int idx = (blk - NEB - NWMB - NRELIN) * 256 + tid;  // < 4096 exactly
    int kc = idx >> 11;
    int nt = (idx >> 9) & 3;
    int L = (idx >> 3) & 63;
    int j = idx & 7;
    int k = kc * 32 + (L >> 4) * 8 + j;          // feat row 0..63
    int c = nt * 16 + (L & 15);                  // out col 0..63
    W1m[idx] = (_Float16)W1[(size_t)k * (2 * DD) + c];
  } else {
    if (tid < BD) query[tid] = qemb[(size_t)r_index[tid >> 5] * DD + (tid & 31)];
  }
}

// log-degree + logsum; wave-per-node coalesced PREDICATED reads, 16 nodes/wave,
// one same-address atomic per block (98 total).
__global__ __launch_bounds__(1024) void lg_kernel(const int* __restrict__ cnt,
                                                  const int2* __restrict__ ep,
                                                  float* __restrict__ lg,
                                                  float* __restrict__ logsum) {
  const int lane = threadIdx.x & 63;
  const int wv   = threadIdx.x >> 6;           // 0..15
  const int nb   = blockIdx.x * 256 + wv * 16;
  float acc = 0.f;
  for (int it = 0; it < 16; ++it) {
    int n = nb + it;
    if (n < NN) {
      int c = cnt[n];
      int2 e = make_int2(0, 0);
      if (lane < c) e = ep[(size_t)n * CAP + lane];
      float s = __int_as_float(e.y);
      #pragma unroll
      for (int o = 32; o > 0; o >>= 1) s += __shfl_xor(s, o);
      float v = logf(s + 1.0f);
      if (lane == 0) { lg[n] = v; acc += v; }
    }
  }
  __shared__ float red[16];
  if (lane == 0) red[wv] = acc;
  __syncthreads();
  if (threadIdx.x == 0) {
    float t = 0.f;
    #pragma unroll
    for (int i = 0; i < 16; ++i) t += red[i];
    atomicAdd(logsum, t);
  }
}

// ---- butterfly over edge groups + stats + per-wave LDS write (no barrier) --
__device__ __forceinline__ void stats_finish(float* sa, float* qa,
                                             h2v* mx2, h2v* mn2,
                                             int cnn, int eg, int c8,
                                             _Float16* shW) {
  #pragma unroll
  for (int j = 0; j < 8; ++j) {
    sa[j] += __shfl_xor(sa[j], 16);
    qa[j] += __shfl_xor(qa[j], 16);
    sa[j] += __shfl_xor(sa[j], 32);
    qa[j] += __shfl_xor(qa[j], 32);
  }
  #pragma unroll
  for (int u = 0; u < 4; ++u) {
    mx2[u] = h2max(mx2[u], shflx_h2(mx2[u], 16));
    mn2[u] = h2min(mn2[u], shflx_h2(mn2[u], 16));
    mx2[u] = h2max(mx2[u], shflx_h2(mx2[u], 32));
    mn2[u] = h2min(mn2[u], shflx_h2(mn2[u], 32));
  }
  const float invc = 1.0f / (float)(cnn + 1);
  union { half8 v8; h2v h2[4]; } ov;
  #pragma unroll
  for (int u = 0; u < 4; ++u) {
    float mean0 = sa[2 * u] * invc, mean1 = sa[2 * u + 1] * invc;
    float sd0 = sqrtf(fmaxf(qa[2 * u] * invc - mean0 * mean0, EPSF));
    float sd1 = sqrtf(fmaxf(qa[2 * u + 1] * invc - mean1 * mean1, EPSF));
    h2v mpair = {(_Float16)mean0, (_Float16)mean1};
    h2v spair = {(_Float16)sd0, (_Float16)sd1};
    h2v sel = (eg == 0) ? mpair
            : ((eg == 1) ? mx2[u] : ((eg == 2) ? mn2[u] : spair));
    ov.h2[u] = sel;
  }
  ((half8*)shW)[eg * 16 + c8] = ov.v8;
}

// ---- per-wave MFMA epilogue for ONE node: A rows 0-3 = queries b=0..3 ------
// Rows 4-15 of the MFMA are don't-care (MfmaUtil is ~3%, waste is free).
template <bool LAST>
__device__ __forceinline__ void node_epilogue(const _Float16* shW,
                                              const _Float16* hinh,
                                              __half* houth,
                                              const float* lg,
                                              const float* logsum,
                                              const _Float16* Wm,
                                              const float* bias,
                                              const float* query,
                                              const int* h_index,
                                              int n, int lane, bool hzero,
                                              const _Float16* W1m,
                                              const float* b1,
                                              const float* W2,
                                              const float* b2,
                                              float* out,
                                              _Float16* hbufW) {
  const int m = lane & 15;
  const int q = lane >> 4;
  const int b = m & 3;              // rows 0-3 real; 4-15 garbage (ignored)
  const float sc = lg[n] * ((float)NN / logsum[0]);
  const _Float16 one = (_Float16)1.f;
  const _Float16 s1h = (_Float16)sc;
  const _Float16 s2h = (_Float16)(1.0f / fmaxf(sc, 0.01f));
  const _Float16* ssrc = shW + b * 32 + q * 8;

  f32x4 c0 = {0.f, 0.f, 0.f, 0.f};
  f32x4 c1 = {0.f, 0.f, 0.f, 0.f};
  half8 a;
  if (hzero) {
    a = (half8)(_Float16)0.f;
    if (n == h_index[b]) {
      const float* qp = query + b * 32 + q * 8;
      #pragma unroll
      for (int j = 0; j < 8; ++j) a[j] = (_Float16)qp[j];
    }
  } else {
    a = *(const half8*)(hinh + (unsigned)n * BD + b * 32 + q * 8);
  }
  #pragma unroll
  for (int t = 0; t < 13; ++t) {
    if (t > 0) {
      const int slab = (t - 1) >> 2, s = (t - 1) & 3;
      a = *(const half8*)(ssrc + s * 128);
      const _Float16 sch = (slab == 0) ? one : ((slab == 1) ? s1h : s2h);
      half8 sv = {sch, sch, sch, sch, sch, sch, sch, sch};
      a = a * sv;
    }
    half8 b0 = *(const half8*)(Wm + (unsigned)(t * 2 + 0) * 512 + lane * 8);
    half8 b1f = *(const half8*)(Wm + (unsigned)(t * 2 + 1) * 512 + lane * 8);
    c0 = __builtin_amdgcn_mfma_f32_16x16x32_f16(a, b0, c0, 0, 0, 0);
    c1 = __builtin_amdgcn_mfma_f32_16x16x32_f16(a, b1f, c1, 0, 0, 0);
  }
  const int col = m;
  const float bj0 = bias[col], bj1 = bias[col + 16];
  if constexpr (!LAST) {
    if (lane < 16) {                // C rows 0-3 live in lanes 0-15
      #pragma unroll
      for (int i = 0; i < 4; ++i) {
        __half* dst = houth + (unsigned)n * BD + i * 32 + col;
        dst[0]  = __float2half(fmaxf(c0[i] + bj0, 0.f));
        dst[16] = __float2half(fmaxf(c1[i] + bj1, 0.f));
      }
    }
  } else {
    if (lane < 16) {
      #pragma unroll
      for (int i = 0; i < 4; ++i) {
        hbufW[i * 32 + col]      = (_Float16)fmaxf(c0[i] + bj0, 0.f);
        hbufW[i * 32 + 16 + col] = (_Float16)fmaxf(c1[i] + bj1, 0.f);
      }
    }
    half8 ah = *(const half8*)(hbufW + b * 32 + q * 8);
    half8 aq;
    const float* qp = query + b * 32 + q * 8;
    #pragma unroll
    for (int j = 0; j < 8; ++j) aq[j] = (_Float16)qp[j];
    f32x4 h1c[4];
    #pragma unroll
    for (int nt = 0; nt < 4; ++nt) {
      h1c[nt] = (f32x4){0.f, 0.f, 0.f, 0.f};
      half8 w0 = *(const half8*)(W1m + (unsigned)(0 * 4 + nt) * 512 + lane * 8);
      half8 w1 = *(const half8*)(W1m + (unsigned)(1 * 4 + nt) * 512 + lane * 8);
      h1c[nt] = __builtin_amdgcn_mfma_f32_16x16x32_f16(ah, w0, h1c[nt], 0, 0, 0);
      h1c[nt] = __builtin_amdgcn_mfma_f32_16x16x32_f16(aq, w1, h1c[nt], 0, 0, 0);
    }
    float part[4] = {0.f, 0.f, 0.f, 0.f};
    #pragma unroll
    for (int nt = 0; nt < 4; ++nt) {
      const float bb = b1[nt * 16 + col];
      const float ww = W2[nt * 16 + col];
      #pragma unroll
      for (int i = 0; i < 4; ++i) {
        float v = fmaxf(h1c[nt][i] + bb, 0.f);
        part[i] = fmaf(v, ww, part[i]);
      }
    }
    #pragma unroll
    for (int i = 0; i < 4; ++i) {
      part[i] += __shfl_xor(part[i], 1);
      part[i] += __shfl_xor(part[i], 2);
      part[i] += __shfl_xor(part[i], 4);
      part[i] += __shfl_xor(part[i], 8);
    }
    if (lane == 0) {
      const float b2v = b2[0];
      #pragma unroll
      for (int i = 0; i < 4; ++i)
        out[(unsigned)i * NN + n] = part[i] + b2v;
    }
  }
}

// ---------------- fused layer 1: independent wave-per-node -----------------
__global__ __launch_bounds__(256, 4) void layer1_fused_kernel(
    const int4* __restrict__ rel4, const int2* __restrict__ ep,
    const int* __restrict__ cnt, const int* __restrict__ h_index,
    const float* __restrict__ query, const float* __restrict__ lg,
    const float* __restrict__ logsum, const _Float16* __restrict__ Wm,
    const float* __restrict__ bias, __half* __restrict__ houth) {
  __shared__ __align__(16) _Float16 shAll[4][512];
  const int tid = threadIdx.x;
  const int lane = tid & 63;
  const int wid = tid >> 6;
  const int c8 = lane & 15;
  const int eg = lane >> 4;
  const int n = blockIdx.x * 4 + wid;
  _Float16* shW = shAll[wid];
  const int hb = h_index[c8 >> 2];
  const int cnn = __builtin_amdgcn_readfirstlane(cnt[n]);
  int2 myE = make_int2(0, 0);
  if (lane < cnn) myE = ep[n * CAP + lane];
  const float4* q4 = (const float4*)query;
  float4 qA = q4[c8 * 2], qB = q4[c8 * 2 + 1];
  float q8[8] = {qA.x, qA.y, qA.z, qA.w, qB.x, qB.y, qB.z, qB.w};
  h2v q2h[4];
  #pragma unroll
  for (int u = 0; u < 4; ++u)
    q2h[u] = (h2v){(_Float16)q8[2 * u], (_Float16)q8[2 * u + 1]};
  const bool g0 = (eg == 0);
  const bool head = (n == hb);
  const _Float16 HI = (_Float16)65504.f;
  const float onef = 1.0f;
  float sa[8], qa[8];
  h2v mx2[4], mn2[4];
  #pragma unroll
  for (int u = 0; u < 4; ++u) {
    float mv0 = (g0 && head) ? q8[2 * u] : 0.f;
    float mv1 = (g0 && head) ? q8[2 * u + 1] : 0.f;
    sa[2 * u] = mv0; sa[2 * u + 1] = mv1;
    qa[2 * u] = mv0 * mv0; qa[2 * u + 1] = mv1 * mv1;
    h2v mvh = {(_Float16)mv0, (_Float16)mv1};
    mx2[u] = g0 ? mvh : (h2v){-HI, -HI};
    mn2[u] = g0 ? mvh : (h2v){HI, HI};
  }
  const int nf = cnn >> 2;
  const int tail = cnn & 3;
  for (int gbase = 0; gbase < nf; gbase += L1BATCH) {
    const int gb = min(L1BATCH, nf - gbase);
    int4 Rv[L1BATCH]; float wv[L1BATCH];
    #pragma unroll
    for (int j = 0; j < L1BATCH; ++j) {
      if (j < gb) {
        int sl = (gbase + j) * 4 + eg;
        int ex = __shfl(myE.x, sl);
        int ey = __shfl(myE.y, sl);
        bool mt = ((ex & 0x7fff) == hb);
        unsigned rr = mt ? ((unsigned)ex >> 15) : 0u;
        wv[j] = mt ? __int_as_float(ey) : 0.f;   // non-match msg==0: exact
        Rv[j] = rel4[rr * 16 + c8];
      }
    }
    #pragma unroll
    for (int j = 0; j < L1BATCH; ++j) {
      if (j < gb) {
        _Float16 wh = (_Float16)wv[j];
        h2v w2 = {wh, wh};
        const h2v* rp = (const h2v*)&Rv[j];
        #pragma unroll
        for (int u = 0; u < 4; ++u) {
          h2v m2 = q2h[u] * rp[u];
          h2v mw2 = m2 * w2;
          mx2[u] = h2max(mx2[u], mw2);
          mn2[u] = h2min(mn2[u], mw2);
          sa[2 * u]     = fmix_lo(sa[2 * u], mw2, onef);
          sa[2 * u + 1] = fmix_hi(sa[2 * u + 1], mw2, onef);
          qa[2 * u]     = fmix2_lo(qa[2 * u], m2, mw2);
          qa[2 * u + 1] = fmix2_hi(qa[2 * u + 1], m2, mw2);
        }
      }
    }
  }
  if (tail) {
    int sl = (cnn & ~3) + eg;
    int ex = __shfl(myE.x, sl);
    int ey = __shfl(myE.y, sl);
    bool act = eg < tail;
    bool mt = act && ((ex & 0x7fff) == hb);
    unsigned rr = mt ? ((unsigned)ex >> 15) : 0u;
    float w = mt ? __int_as_float(ey) : 0.f;
    int4 Rv = rel4[rr * 16 + c8];
    _Float16 wh = (_Float16)w;
    h2v w2 = {wh, wh};
    const h2v* rp = (const h2v*)&Rv;
    #pragma unroll
    for (int u = 0; u < 4; ++u) {
      h2v m2 = q2h[u] * rp[u];
      h2v mw2 = m2 * w2;
      if (act) {
        mx2[u] = h2max(mx2[u], mw2);
        mn2[u] = h2min(mn2[u], mw2);
      }
      sa[2 * u]     = fmix_lo(sa[2 * u], mw2, onef);
      sa[2 * u + 1] = fmix_hi(sa[2 * u + 1], mw2, onef);
      qa[2 * u]     = fmix2_lo(qa[2 * u], m2, mw2);
      qa[2 * u + 1] = fmix2_hi(qa[2 * u + 1], m2, mw2);
    }
  }
  stats_finish(sa, qa, mx2, mn2, cnn, eg, c8, shW);
  // no barrier: per-wave LDS region, compiler-inserted lgkmcnt orders it
  node_epilogue<false>(shW, nullptr, houth, lg, logsum, Wm, bias, query,
                       h_index, n, lane, true,
                       nullptr, nullptr, nullptr, nullptr, nullptr, nullptr);
}

// ---------------- fused generic layer: independent wave-per-node -----------
template <bool LAST>
__global__ __launch_bounds__(256, 4) void layer_fused_kernel(
    const int4* __restrict__ hin4, const int4* __restrict__ rel4,
    const int2* __restrict__ ep, const int* __restrict__ cnt,
    const int* __restrict__ h_index, const float* __restrict__ query,
    const float* __restrict__ lg, const float* __restrict__ logsum,
    const _Float16* __restrict__ Wm, const float* __restrict__ bias,
    __half* __restrict__ houth,
    const _Float16* __restrict__ W1m, const float* __restrict__ b1,
    const float* __restrict__ W2, const float* __restrict__ b2,
    float* __restrict__ out) {
  __shared__ __align__(16) _Float16 shAll[4][512];
  __shared__ __align__(16) _Float16 hbufAll[4][128];
  const int tid = threadIdx.x;
  const int lane = tid & 63;
  const int wid = tid >> 6;
  const int c8 = lane & 15;
  const int eg = lane >> 4;
  const int n = blockIdx.x * 4 + wid;
  _Float16* shW = shAll[wid];
  const int hb = h_index[c8 >> 2];
  const int cnn = __builtin_amdgcn_readfirstlane(cnt[n]);
  int2 myE = make_int2(0, 0);
  if (lane < cnn) myE = ep[n * CAP + lane];
  const float4* q4 = (const float4*)query;
  float4 qA = q4[c8 * 2], qB = q4[c8 * 2 + 1];
  float q8[8] = {qA.x, qA.y, qA.z, qA.w, qB.x, qB.y, qB.z, qB.w};
  const bool g0 = (eg == 0);
  const bool head = (n == hb);
  const _Float16 HI = (_Float16)65504.f;
  const float onef = 1.0f;
  float sa[8], qa[8];
  h2v mx2[4], mn2[4];
  #pragma unroll
  for (int u = 0; u < 4; ++u) {
    float mv0 = (g0 && head) ? q8[2 * u] : 0.f;
    float mv1 = (g0 && head) ? q8[2 * u + 1] : 0.f;
    sa[2 * u] = mv0; sa[2 * u + 1] = mv1;
    qa[2 * u] = mv0 * mv0; qa[2 * u + 1] = mv1 * mv1;
    h2v mvh = {(_Float16)mv0, (_Float16)mv1};
    mx2[u] = g0 ? mvh : (h2v){-HI, -HI};
    mn2[u] = g0 ? mvh : (h2v){HI, HI};
  }
  const int nf = cnn >> 2;
  const int tail = cnn & 3;
  for (int gbase = 0; gbase < nf; gbase += GBATCH) {
    const int gb = min(GBATCH, nf - gbase);
    int4 Hv[GBATCH], Rv[GBATCH]; float wv[GBATCH];
    #pragma unroll
    for (int j = 0; j < GBATCH; ++j) {
      if (j < gb) {
        int sl = (gbase + j) * 4 + eg;
        int ex = __shfl(myE.x, sl);
        wv[j] = __int_as_float(__shfl(myE.y, sl));
        int src = ex & 0x7fff;
        unsigned rr = (unsigned)ex >> 15;
        Hv[j] = hin4[(unsigned)src * 16 + c8];
        Rv[j] = rel4[rr * 16 + c8];
      }
    }
    #pragma unroll
    for (int j = 0; j < GBATCH; ++j) {
      if (j < gb) {
        _Float16 wh = (_Float16)wv[j];
        h2v w2 = {wh, wh};
        const h2v* hp = (const h2v*)&Hv[j];
        const h2v* rp = (const h2v*)&Rv[j];
        #pragma unroll
        for (int u = 0; u < 4; ++u) {
          h2v m2 = hp[u] * rp[u];
          h2v mw2 = m2 * w2;
          mx2[u] = h2max(mx2[u], mw2);
          mn2[u] = h2min(mn2[u], mw2);
          sa[2 * u]     = fmix_lo(sa[2 * u], mw2, onef);
          sa[2 * u + 1] = fmix_hi(sa[2 * u + 1], mw2, onef);
          qa[2 * u]     = fmix2_lo(qa[2 * u], m2, mw2);
          qa[2 * u + 1] = fmix2_hi(qa[2 * u + 1], m2, mw2);
        }
      }
    }
  }
  if (tail) {
    int sl = (cnn & ~3) + eg;
    int ex = __shfl(myE.x, sl);
    int ey = __shfl(myE.y, sl);
    bool act = eg < tail;
    int src = act ? (ex & 0x7fff) : 0;
    unsigned rr = act ? ((unsigned)ex >> 15) : 0u;
    float w = act ? __int_as_float(ey) : 0.f;
    int4 Hv = hin4[(unsigned)src * 16 + c8];
    int4 Rv = rel4[rr * 16 + c8];
    _Float16 wh = (_Float16)w;
    h2v w2 = {wh, wh};
    const h2v* hp = (const h2v*)&Hv;
    const h2v* rp = (const h2v*)&Rv;
    #pragma unroll
    for (int u = 0; u < 4; ++u) {
      h2v m2 = hp[u] * rp[u];
      h2v mw2 = m2 * w2;
      if (act) {
        mx2[u] = h2max(mx2[u], mw2);
        mn2[u] = h2min(mn2[u], mw2);
      }
      sa[2 * u]     = fmix_lo(sa[2 * u], mw2, onef);
      sa[2 * u + 1] = fmix_hi(sa[2 * u + 1], mw2, onef);
      qa[2 * u]     = fmix2_lo(qa[2 * u], m2, mw2);
      qa[2 * u + 1] = fmix2_hi(qa[2 * u + 1], m2, mw2);
    }
  }
  stats_finish(sa, qa, mx2, mn2, cnn, eg, c8, shW);
  node_epilogue<LAST>(shW, (const _Float16*)hin4, houth, lg, logsum, Wm, bias,
                      query, h_index, n, lane, false,
                      W1m, b1, W2, b2, out, hbufAll[wid]);
}

extern "C" void kernel_launch(void* const* d_in, const int* in_sizes, int n_in,
                              void* d_out, int out_size, void* d_ws, size_t ws_size,
                              hipStream_t stream) {
  const int*   node_in  = (const int*)d_in[0];
  const int*   node_out = (const int*)d_in[1];
  const int*   relation = (const int*)d_in[2];
  const float* ew       = (const float*)d_in[3];
  const int*   h_index  = (const int*)d_in[4];
  const int*   r_index  = (const int*)d_in[5];
  const float* qemb     = (const float*)d_in[6];
  const float* relW     = (const float*)d_in[7];
  const float* relB     = (const float*)d_in[8];
  const float* linW     = (const float*)d_in[9];
  const float* linB     = (const float*)d_in[10];
  const float* W1       = (const float*)d_in[11];
  const float* b1       = (const float*)d_in[12];
  const float* W2       = (const float*)d_in[13];
  const float* b2       = (const float*)d_in[14];
  float* out = (float*)d_out;

  char* ws = (char*)d_ws;
  size_t off = 0;
  auto alloc = [&](size_t bytes) -> char* {
    char* p = ws + off;
    off += (bytes + 255) & ~(size_t)255;
    return p;
  };
  __half*   h0     = (__half*)  alloc((size_t)NN * BD * 2);
  __half*   h1buf  = (__half*)  alloc((size_t)NN * BD * 2);
  __half*   relIn  = (__half*)  alloc((size_t)LL * R2C * BD * 2);
  _Float16* Wm     = (_Float16*)alloc((size_t)LL * WMH * 2);
  _Float16* W1m    = (_Float16*)alloc((size_t)4096 * 2);
  int2*     ep     = (int2*)    alloc((size_t)NN * CAP * 8);
  int*      cnti   = (int*)     alloc((size_t)NN * 4);
  float*    stats  = (float*)   alloc(256);   // [0]=logsum (contiguous w/ cnti)
  float*    lg     = (float*)   alloc((size_t)NN * 4);
  float*    query  = (float*)   alloc((size_t)BD * 4);

  float* logsum = stats;

  // cnti and stats are contiguous (cnti padded to 256): one memset clears both
  hipMemsetAsync(cnti, 0, (((size_t)NN * 4 + 255) & ~(size_t)255) + 256, stream);

  build_setup_kernel<<<NEB + NWMB + NRELIN + NW1P + 1, 256, 0, stream>>>(
      node_in, node_out, relation, ew, cnti, ep,
      linW, Wm, r_index, qemb, relW, relB, relIn, query, W1, W1m);
  lg_kernel<<<98, 1024, 0, stream>>>(cnti, ep, lg, logsum);

  __half* hin = h0; __half* hout = h1buf;
  for (int l = 0; l < LL; ++l) {
    if (l == 0) {
      layer1_fused_kernel<<<NN / 4, 256, 0, stream>>>(
          (const int4*)relIn, ep, cnti, h_index, query, lg, logsum,
          Wm, linB, hout);
    } else if (l < LL - 1) {
      layer_fused_kernel<false><<<NN / 4, 256, 0, stream>>>(
          (const int4*)hin, (const int4*)relIn + (size_t)l * R2C * 16,
          ep, cnti, h_index, query, lg, logsum,
          Wm + (size_t)l * WMH, linB + (size_t)l * DD, hout,
          nullptr, nullptr, nullptr, nullptr, nullptr);
    } else {
      layer_fused_kernel<true><<<NN / 4, 256, 0, stream>>>(
          (const int4*)hin, (const int4*)relIn + (size_t)l * R2C * 16,
          ep, cnti, h_index, query, lg, logsum,
          Wm + (size_t)l * WMH, linB + (size_t)l * DD, hout,
          W1m, b1, W2, b2, out);
    }
    __half* tmp = hin; hin = hout; hout = tmp;
  }
}

// Round 10
// 278.061 us; speedup vs baseline: 1.1770x; 1.1770x over previous
//
#include <hip/hip_runtime.h>
#include <hip/hip_fp16.h>

#define NN  25000
#define EE  500000
#define BB  4
#define DD  32
#define LL  4
#define R2C 474
#define BD  128      // B*D
#define THD 416      // 13*D
#define EPSF 1e-6f
#define WMH 13312    // halfs per layer of MFMA-packed W: 13 t * 2 nt * 64 * 8
#define CAP 64       // fixed CSR segment capacity (max degree ~45 for Poisson(20))
#define GBATCH 5     // generic-layer prefetch depth (slot groups of 4 edges)
#define L1BATCH 8    // layer1 prefetch depth

// merged build+setup grid partition
#define NEB    245   // ceil(EE/8 / 256), 8 edges/thread
#define NWMB   208   // LL*WMH / 256
#define NRELIN 948   // LL*R2C*BD / 256
#define NW1P   16    // 4096 / 256

typedef _Float16 half8 __attribute__((ext_vector_type(8)));
typedef _Float16 h2v   __attribute__((ext_vector_type(2)));
typedef float    f32x4 __attribute__((ext_vector_type(4)));

// packed fp16 max/min (no __hmax2/__hmin2 in ROCm's fp16 header)
__device__ __forceinline__ h2v h2max(h2v a, h2v b) {
  h2v d; asm("v_pk_max_f16 %0, %1, %2" : "=v"(d) : "v"(a), "v"(b)); return d;
}
__device__ __forceinline__ h2v h2min(h2v a, h2v b) {
  h2v d; asm("v_pk_min_f16 %0, %1, %2" : "=v"(d) : "v"(a), "v"(b)); return d;
}
__device__ __forceinline__ h2v shflx_h2(h2v v, int m) {
  union { h2v h; int i; } u; u.h = v;
  u.i = __shfl_xor(u.i, m);
  return u.h;
}
// f32 acc += f16(lo/hi of x) * onef  — single-instruction mixed fma
__device__ __forceinline__ float fmix_lo(float acc, h2v x, float onef) {
  asm("v_fma_mix_f32 %0, %1, %2, %0 op_sel:[0,0,0] op_sel_hi:[1,0,0]"
      : "+v"(acc) : "v"(x), "v"(onef));
  return acc;
}
__device__ __forceinline__ float fmix_hi(float acc, h2v x, float onef) {
  asm("v_fma_mix_f32 %0, %1, %2, %0 op_sel:[1,0,0] op_sel_hi:[1,0,0]"
      : "+v"(acc) : "v"(x), "v"(onef));
  return acc;
}
// f32 acc += f16(a) * f16(b) (lo/hi halves)
__device__ __forceinline__ float fmix2_lo(float acc, h2v a, h2v b) {
  asm("v_fma_mix_f32 %0, %1, %2, %0 op_sel:[0,0,0] op_sel_hi:[1,1,0]"
      : "+v"(acc) : "v"(a), "v"(b));
  return acc;
}
__device__ __forceinline__ float fmix2_hi(float acc, h2v a, h2v b) {
  asm("v_fma_mix_f32 %0, %1, %2, %0 op_sel:[1,1,0] op_sel_hi:[1,1,0]"
      : "+v"(acc) : "v"(a), "v"(b));
  return acc;
}

// ---------------- merged graph build + all query-side setup ----------------
__global__ __launch_bounds__(256) void build_setup_kernel(
    const int* __restrict__ node_in, const int* __restrict__ node_out,
    const int* __restrict__ relation, const float* __restrict__ ew,
    int* __restrict__ cnt, int2* __restrict__ ep,
    const float* __restrict__ linW, _Float16* __restrict__ Wm,
    const int* __restrict__ r_index, const float* __restrict__ qemb,
    const float* __restrict__ relW, const float* __restrict__ relB,
    __half* __restrict__ relIn, float* __restrict__ query,
    const float* __restrict__ W1, _Float16* __restrict__ W1m) {
  const int blk = blockIdx.x;
  const int tid = threadIdx.x;
  if (blk < NEB) {
    int i = blk * 256 + tid;                     // edge-octet index
    if (i >= EE / 8) return;
    const int4*   ni4 = (const int4*)node_in;
    const int4*   no4 = (const int4*)node_out;
    const int4*   rl4 = (const int4*)relation;
    const float4* ew4 = (const float4*)ew;
    int4   noA = no4[2 * i], noB = no4[2 * i + 1];
    int4   niA = ni4[2 * i], niB = ni4[2 * i + 1];
    int4   rlA = rl4[2 * i], rlB = rl4[2 * i + 1];
    float4 ewA = ew4[2 * i], ewB = ew4[2 * i + 1];
    int s0 = atomicAdd(&cnt[noA.x], 1);
    int s1 = atomicAdd(&cnt[noA.y], 1);
    int s2 = atomicAdd(&cnt[noA.z], 1);
    int s3 = atomicAdd(&cnt[noA.w], 1);
    int s4 = atomicAdd(&cnt[noB.x], 1);
    int s5 = atomicAdd(&cnt[noB.y], 1);
    int s6 = atomicAdd(&cnt[noB.z], 1);
    int s7 = atomicAdd(&cnt[noB.w], 1);
    ep[noA.x * CAP + s0] = make_int2(niA.x | (rlA.x << 15), __float_as_int(ewA.x));
    ep[noA.y * CAP + s1] = make_int2(niA.y | (rlA.y << 15), __float_as_int(ewA.y));
    ep[noA.z * CAP + s2] = make_int2(niA.z | (rlA.z << 15), __float_as_int(ewA.z));
    ep[noA.w * CAP + s3] = make_int2(niA.w | (rlA.w << 15), __float_as_int(ewA.w));
    ep[noB.x * CAP + s4] = make_int2(niB.x | (rlB.x << 15), __float_as_int(ewB.x));
    ep[noB.y * CAP + s5] = make_int2(niB.y | (rlB.y << 15), __float_as_int(ewB.y));
    ep[noB.z * CAP + s6] = make_int2(niB.z | (rlB.z << 15), __float_as_int(ewB.z));
    ep[noB.w * CAP + s7] = make_int2(niB.w | (rlB.w << 15), __float_as_int(ewB.w));
  } else if (blk < NEB + NWMB) {
    int idx = (blk - NEB) * 256 + tid;           // < LL*WMH exactly
    int l = idx / WMH, rest = idx % WMH;
    int t = rest >> 10;
    int nt = (rest >> 9) & 1;
    int L = (rest >> 3) & 63;
    int j = rest & 7;
    int k = t * 32 + (L >> 4) * 8 + j;
    int n = nt * 16 + (L & 15);
    int wrow;
    if (k < 32) wrow = k;
    else {
      int kk = k - 32;
      int slab = kk >> 7, s = (kk >> 5) & 3, dd = kk & 31;
      wrow = DD + (dd * 4 + s) * 3 + slab;
    }
    Wm[idx] = (_Float16)linW[(size_t)l * THD * DD + (size_t)wrow * DD + n];
  } else if (blk < NEB + NWMB + NRELIN) {
    int o = (blk - NEB - NWMB) * 256 + tid;      // < LL*R2C*BD exactly
    int l = o / (R2C * BD);
    int rest = o % (R2C * BD);
    int r = rest >> 7, b = (rest >> 5) & 3, d = rest & 31;
    int col = r * DD + d;
    const float* W = relW + (size_t)l * DD * R2C * DD;
    const float* qrow = qemb + (size_t)r_index[b] * DD;
    float acc = relB[(size_t)l * R2C * DD + col];
    #pragma unroll
    for (int k = 0; k < DD; ++k)
      acc = fmaf(qrow[k], W[(size_t)k * (R2C * DD) + col], acc);
    relIn[o] = __float2half(acc);
  } else if (blk < NEB + NWMB + NRELIN + NW1P) {
    int idx = (blk - NEB - NWMB - NRELIN) * 256 + tid;  // < 4096 exactly
    int kc = idx >> 11;
    int nt = (idx >> 9) & 3;
    int L = (idx >> 3) & 63;
    int j = idx & 7;
    int k = kc * 32 + (L >> 4) * 8 + j;          // feat row 0..63
    int c = nt * 16 + (L & 15);                  // out col 0..63
    W1m[idx] = (_Float16)W1[(size_t)k * (2 * DD) + c];
  } else {
    if (tid < BD) query[tid] = qemb[(size_t)r_index[tid >> 5] * DD + (tid & 31)];
  }
}

// log-degree + logsum; wave-per-node coalesced PREDICATED reads, 16 nodes/wave,
// one same-address atomic per block (98 total).
__global__ __launch_bounds__(1024) void lg_kernel(const int* __restrict__ cnt,
                                                  const int2* __restrict__ ep,
                                                  float* __restrict__ lg,
                                                  float* __restrict__ logsum) {
  const int lane = threadIdx.x & 63;
  const int wv   = threadIdx.x >> 6;           // 0..15
  const int nb   = blockIdx.x * 256 + wv * 16;
  float acc = 0.f;
  for (int it = 0; it < 16; ++it) {
    int n = nb + it;
    if (n < NN) {
      int c = cnt[n];
      int2 e = make_int2(0, 0);
      if (lane < c) e = ep[(size_t)n * CAP + lane];
      float s = __int_as_float(e.y);
      #pragma unroll
      for (int o = 32; o > 0; o >>= 1) s += __shfl_xor(s, o);
      float v = logf(s + 1.0f);
      if (lane == 0) { lg[n] = v; acc += v; }
    }
  }
  __shared__ float red[16];
  if (lane == 0) red[wv] = acc;
  __syncthreads();
  if (threadIdx.x == 0) {
    float t = 0.f;
    #pragma unroll
    for (int i = 0; i < 16; ++i) t += red[i];
    atomicAdd(logsum, t);
  }
}

// ---- shared MFMA epilogue: one wave computes 16x32 linear for 4 nodes ----
template <bool LAST>
__device__ __forceinline__ void mfma_epilogue(const _Float16* sh,
                                              const _Float16* hinh,
                                              __half* houth,
                                              const float* lg,
                                              const float* logsum,
                                              const _Float16* Wm,
                                              const float* bias,
                                              const float* query,
                                              const int* h_index,
                                              int nbase, int lane, bool hzero,
                                              const _Float16* W1m,
                                              const float* b1,
                                              const float* W2,
                                              const float* b2,
                                              float* out,
                                              _Float16* hbuf) {
  const int m = lane & 15;
  const int q = lane >> 4;
  const int nl = m >> 2;
  const int n = nbase + nl;
  const int b = m & 3;
  const float sc = lg[n] * ((float)NN / logsum[0]);
  const _Float16 one = (_Float16)1.f;
  const _Float16 s1h = (_Float16)sc;
  const _Float16 s2h = (_Float16)(1.0f / fmaxf(sc, 0.01f));
  const _Float16* ssrc = sh + nl * 512 + b * 32 + q * 8;

  f32x4 c0 = {0.f, 0.f, 0.f, 0.f};
  f32x4 c1 = {0.f, 0.f, 0.f, 0.f};
  half8 a;
  if (hzero) {
    a = (half8)(_Float16)0.f;
    if (n == h_index[b]) {
      const float* qp = query + b * 32 + q * 8;
      #pragma unroll
      for (int j = 0; j < 8; ++j) a[j] = (_Float16)qp[j];
    }
  } else {
    a = *(const half8*)(hinh + (unsigned)n * BD + b * 32 + q * 8);
  }
  #pragma unroll
  for (int t = 0; t < 13; ++t) {
    if (t > 0) {
      const int slab = (t - 1) >> 2, s = (t - 1) & 3;
      a = *(const half8*)(ssrc + s * 128);
      const _Float16 sch = (slab == 0) ? one : ((slab == 1) ? s1h : s2h);
      half8 sv = {sch, sch, sch, sch, sch, sch, sch, sch};
      a = a * sv;
    }
    half8 b0 = *(const half8*)(Wm + (unsigned)(t * 2 + 0) * 512 + lane * 8);
    half8 b1f = *(const half8*)(Wm + (unsigned)(t * 2 + 1) * 512 + lane * 8);
    c0 = __builtin_amdgcn_mfma_f32_16x16x32_f16(a, b0, c0, 0, 0, 0);
    c1 = __builtin_amdgcn_mfma_f32_16x16x32_f16(a, b1f, c1, 0, 0, 0);
  }
  const int col = lane & 15;
  const float bj0 = bias[col], bj1 = bias[col + 16];
  if constexpr (!LAST) {
    #pragma unroll
    for (int i = 0; i < 4; ++i) {
      const int mr = q * 4 + i;
      __half* dst = houth + (unsigned)(nbase + (mr >> 2)) * BD + (mr & 3) * 32 + col;
      dst[0]  = __float2half(fmaxf(c0[i] + bj0, 0.f));
      dst[16] = __float2half(fmaxf(c1[i] + bj1, 0.f));
    }
  } else {
    #pragma unroll
    for (int i = 0; i < 4; ++i) {
      const int mr = q * 4 + i;
      hbuf[mr * 32 + col]      = (_Float16)fmaxf(c0[i] + bj0, 0.f);
      hbuf[mr * 32 + 16 + col] = (_Float16)fmaxf(c1[i] + bj1, 0.f);
    }
    half8 ah = *(const half8*)(hbuf + m * 32 + q * 8);
    half8 aq;
    const float* qp = query + b * 32 + q * 8;
    #pragma unroll
    for (int j = 0; j < 8; ++j) aq[j] = (_Float16)qp[j];
    f32x4 h1c[4];
    #pragma unroll
    for (int nt = 0; nt < 4; ++nt) {
      h1c[nt] = (f32x4){0.f, 0.f, 0.f, 0.f};
      half8 w0 = *(const half8*)(W1m + (unsigned)(0 * 4 + nt) * 512 + lane * 8);
      half8 w1 = *(const half8*)(W1m + (unsigned)(1 * 4 + nt) * 512 + lane * 8);
      h1c[nt] = __builtin_amdgcn_mfma_f32_16x16x32_f16(ah, w0, h1c[nt], 0, 0, 0);
      h1c[nt] = __builtin_amdgcn_mfma_f32_16x16x32_f16(aq, w1, h1c[nt], 0, 0, 0);
    }
    float part[4] = {0.f, 0.f, 0.f, 0.f};
    #pragma unroll
    for (int nt = 0; nt < 4; ++nt) {
      const float bb = b1[nt * 16 + col];
      const float ww = W2[nt * 16 + col];
      #pragma unroll
      for (int i = 0; i < 4; ++i) {
        float v = fmaxf(h1c[nt][i] + bb, 0.f);
        part[i] = fmaf(v, ww, part[i]);
      }
    }
    #pragma unroll
    for (int i = 0; i < 4; ++i) {
      part[i] += __shfl_xor(part[i], 1);
      part[i] += __shfl_xor(part[i], 2);
      part[i] += __shfl_xor(part[i], 4);
      part[i] += __shfl_xor(part[i], 8);
    }
    if (col == 0) {
      const float b2v = b2[0];
      #pragma unroll
      for (int i = 0; i < 4; ++i)
        out[(unsigned)i * NN + nbase + q] = part[i] + b2v;
    }
  }
}

// ---- shared tail: butterfly over edge groups + stats + sh write ----------
__device__ __forceinline__ void stats_finish(float* sa, float* qa,
                                             h2v* mx2, h2v* mn2,
                                             int cnn, int wid, int eg, int c8,
                                             void* sh) {
  #pragma unroll
  for (int j = 0; j < 8; ++j) {
    sa[j] += __shfl_xor(sa[j], 16);
    qa[j] += __shfl_xor(qa[j], 16);
    sa[j] += __shfl_xor(sa[j], 32);
    qa[j] += __shfl_xor(qa[j], 32);
  }
  #pragma unroll
  for (int u = 0; u < 4; ++u) {
    mx2[u] = h2max(mx2[u], shflx_h2(mx2[u], 16));
    mn2[u] = h2min(mn2[u], shflx_h2(mn2[u], 16));
    mx2[u] = h2max(mx2[u], shflx_h2(mx2[u], 32));
    mn2[u] = h2min(mn2[u], shflx_h2(mn2[u], 32));
  }
  const float invc = 1.0f / (float)(cnn + 1);
  union { half8 v8; h2v h2[4]; } ov;
  #pragma unroll
  for (int u = 0; u < 4; ++u) {
    float mean0 = sa[2 * u] * invc, mean1 = sa[2 * u + 1] * invc;
    float sd0 = sqrtf(fmaxf(qa[2 * u] * invc - mean0 * mean0, EPSF));
    float sd1 = sqrtf(fmaxf(qa[2 * u + 1] * invc - mean1 * mean1, EPSF));
    h2v mpair = {(_Float16)mean0, (_Float16)mean1};
    h2v spair = {(_Float16)sd0, (_Float16)sd1};
    h2v sel = (eg == 0) ? mpair
            : ((eg == 1) ? mx2[u] : ((eg == 2) ? mn2[u] : spair));
    ov.h2[u] = sel;
  }
  ((half8*)sh)[wid * 64 + eg * 16 + c8] = ov.v8;
}

// ---------------- fused layer 1: packed 4-edge gather + MFMA ---------------
__global__ __launch_bounds__(256, 4) void layer1_fused_kernel(
    const int4* __restrict__ rel4, const int2* __restrict__ ep,
    const int* __restrict__ cnt, const int* __restrict__ h_index,
    const float* __restrict__ query, const float* __restrict__ lg,
    const float* __restrict__ logsum, const _Float16* __restrict__ Wm,
    const float* __restrict__ bias, __half* __restrict__ houth) {
  __shared__ __align__(16) __half2 sh[4][256];
  const int tid = threadIdx.x;
  const int lane = tid & 63;
  const int wid = tid >> 6;
  const int c8 = lane & 15;
  const int eg = lane >> 4;
  const int nbase = blockIdx.x * 4;
  const int n = nbase + wid;
  const int hb = h_index[c8 >> 2];
  const int cnn = __builtin_amdgcn_readfirstlane(cnt[n]);
  int2 myE = make_int2(0, 0);
  if (lane < cnn) myE = ep[n * CAP + lane];
  const float4* q4 = (const float4*)query;
  float4 qA = q4[c8 * 2], qB = q4[c8 * 2 + 1];
  float q8[8] = {qA.x, qA.y, qA.z, qA.w, qB.x, qB.y, qB.z, qB.w};
  h2v q2h[4];
  #pragma unroll
  for (int u = 0; u < 4; ++u)
    q2h[u] = (h2v){(_Float16)q8[2 * u], (_Float16)q8[2 * u + 1]};
  const bool g0 = (eg == 0);
  const bool head = (n == hb);
  const _Float16 HI = (_Float16)65504.f;
  const float onef = 1.0f;
  float sa[8], qa[8];
  h2v mx2[4], mn2[4];
  #pragma unroll
  for (int u = 0; u < 4; ++u) {
    float mv0 = (g0 && head) ? q8[2 * u] : 0.f;
    float mv1 = (g0 && head) ? q8[2 * u + 1] : 0.f;
    sa[2 * u] = mv0; sa[2 * u + 1] = mv1;
    qa[2 * u] = mv0 * mv0; qa[2 * u + 1] = mv1 * mv1;
    h2v mvh = {(_Float16)mv0, (_Float16)mv1};
    mx2[u] = g0 ? mvh : (h2v){-HI, -HI};
    mn2[u] = g0 ? mvh : (h2v){HI, HI};
  }
  const int nf = cnn >> 2;
  const int tail = cnn & 3;
  for (int gbase = 0; gbase < nf; gbase += L1BATCH) {
    const int gb = min(L1BATCH, nf - gbase);
    int4 Rv[L1BATCH]; float wv[L1BATCH];
    #pragma unroll
    for (int j = 0; j < L1BATCH; ++j) {
      if (j < gb) {
        int sl = (gbase + j) * 4 + eg;
        int ex = __shfl(myE.x, sl);
        int ey = __shfl(myE.y, sl);
        bool mt = ((ex & 0x7fff) == hb);
        unsigned rr = mt ? ((unsigned)ex >> 15) : 0u;
        wv[j] = mt ? __int_as_float(ey) : 0.f;   // non-match msg==0: exact
        Rv[j] = rel4[rr * 16 + c8];
      }
    }
    #pragma unroll
    for (int j = 0; j < L1BATCH; ++j) {
      if (j < gb) {
        _Float16 wh = (_Float16)wv[j];
        h2v w2 = {wh, wh};
        const h2v* rp = (const h2v*)&Rv[j];
        #pragma unroll
        for (int u = 0; u < 4; ++u) {
          h2v m2 = q2h[u] * rp[u];
          h2v mw2 = m2 * w2;
          mx2[u] = h2max(mx2[u], mw2);
          mn2[u] = h2min(mn2[u], mw2);
          sa[2 * u]     = fmix_lo(sa[2 * u], mw2, onef);
          sa[2 * u + 1] = fmix_hi(sa[2 * u + 1], mw2, onef);
          qa[2 * u]     = fmix2_lo(qa[2 * u], m2, mw2);
          qa[2 * u + 1] = fmix2_hi(qa[2 * u + 1], m2, mw2);
        }
      }
    }
  }
  if (tail) {
    int sl = (cnn & ~3) + eg;
    int ex = __shfl(myE.x, sl);
    int ey = __shfl(myE.y, sl);
    bool act = eg < tail;
    bool mt = act && ((ex & 0x7fff) == hb);
    unsigned rr = mt ? ((unsigned)ex >> 15) : 0u;
    float w = mt ? __int_as_float(ey) : 0.f;
    int4 Rv = rel4[rr * 16 + c8];
    _Float16 wh = (_Float16)w;
    h2v w2 = {wh, wh};
    const h2v* rp = (const h2v*)&Rv;
    #pragma unroll
    for (int u = 0; u < 4; ++u) {
      h2v m2 = q2h[u] * rp[u];
      h2v mw2 = m2 * w2;
      if (act) {
        mx2[u] = h2max(mx2[u], mw2);
        mn2[u] = h2min(mn2[u], mw2);
      }
      sa[2 * u]     = fmix_lo(sa[2 * u], mw2, onef);
      sa[2 * u + 1] = fmix_hi(sa[2 * u + 1], mw2, onef);
      qa[2 * u]     = fmix2_lo(qa[2 * u], m2, mw2);
      qa[2 * u + 1] = fmix2_hi(qa[2 * u + 1], m2, mw2);
    }
  }
  stats_finish(sa, qa, mx2, mn2, cnn, wid, eg, c8, (void*)&sh[0][0]);
  __syncthreads();
  if (tid < 64)
    mfma_epilogue<false>((const _Float16*)&sh[0][0], nullptr, houth, lg, logsum,
                         Wm, bias, query, h_index, nbase, lane, true,
                         nullptr, nullptr, nullptr, nullptr, nullptr, nullptr);
}

// ---------------- fused generic layer: packed 4-edge gather + MFMA ---------
template <bool LAST>
__global__ __launch_bounds__(256, 4) void layer_fused_kernel(
    const int4* __restrict__ hin4, const int4* __restrict__ rel4,
    const int2* __restrict__ ep, const int* __restrict__ cnt,
    const int* __restrict__ h_index, const float* __restrict__ query,
    const float* __restrict__ lg, const float* __restrict__ logsum,
    const _Float16* __restrict__ Wm, const float* __restrict__ bias,
    __half* __restrict__ houth,
    const _Float16* __restrict__ W1m, const float* __restrict__ b1,
    const float* __restrict__ W2, const float* __restrict__ b2,
    float* __restrict__ out) {
  __shared__ __align__(16) __half2 sh[4][256];
  __shared__ __align__(16) _Float16 hbuf[512];
  const int tid = threadIdx.x;
  const int lane = tid & 63;
  const int wid = tid >> 6;
  const int c8 = lane & 15;
  const int eg = lane >> 4;
  const int nbase = blockIdx.x * 4;
  const int n = nbase + wid;
  const int hb = h_index[c8 >> 2];
  const int cnn = __builtin_amdgcn_readfirstlane(cnt[n]);
  int2 myE = make_int2(0, 0);
  if (lane < cnn) myE = ep[n * CAP + lane];
  const float4* q4 = (const float4*)query;
  float4 qA = q4[c8 * 2], qB = q4[c8 * 2 + 1];
  float q8[8] = {qA.x, qA.y, qA.z, qA.w, qB.x, qB.y, qB.z, qB.w};
  const bool g0 = (eg == 0);
  const bool head = (n == hb);
  const _Float16 HI = (_Float16)65504.f;
  const float onef = 1.0f;
  float sa[8], qa[8];
  h2v mx2[4], mn2[4];
  #pragma unroll
  for (int u = 0; u < 4; ++u) {
    float mv0 = (g0 && head) ? q8[2 * u] : 0.f;
    float mv1 = (g0 && head) ? q8[2 * u + 1] : 0.f;
    sa[2 * u] = mv0; sa[2 * u + 1] = mv1;
    qa[2 * u] = mv0 * mv0; qa[2 * u + 1] = mv1 * mv1;
    h2v mvh = {(_Float16)mv0, (_Float16)mv1};
    mx2[u] = g0 ? mvh : (h2v){-HI, -HI};
    mn2[u] = g0 ? mvh : (h2v){HI, HI};
  }
  const int nf = cnn >> 2;
  const int tail = cnn & 3;
  for (int gbase = 0; gbase < nf; gbase += GBATCH) {
    const int gb = min(GBATCH, nf - gbase);
    int4 Hv[GBATCH], Rv[GBATCH]; float wv[GBATCH];
    #pragma unroll
    for (int j = 0; j < GBATCH; ++j) {
      if (j < gb) {
        int sl = (gbase + j) * 4 + eg;
        int ex = __shfl(myE.x, sl);
        wv[j] = __int_as_float(__shfl(myE.y, sl));
        int src = ex & 0x7fff;
        unsigned rr = (unsigned)ex >> 15;
        Hv[j] = hin4[(unsigned)src * 16 + c8];
        Rv[j] = rel4[rr * 16 + c8];
      }
    }
    #pragma unroll
    for (int j = 0; j < GBATCH; ++j) {
      if (j < gb) {
        _Float16 wh = (_Float16)wv[j];
        h2v w2 = {wh, wh};
        const h2v* hp = (const h2v*)&Hv[j];
        const h2v* rp = (const h2v*)&Rv[j];
        #pragma unroll
        for (int u = 0; u < 4; ++u) {
          h2v m2 = hp[u] * rp[u];
          h2v mw2 = m2 * w2;
          mx2[u] = h2max(mx2[u], mw2);
          mn2[u] = h2min(mn2[u], mw2);
          sa[2 * u]     = fmix_lo(sa[2 * u], mw2, onef);
          sa[2 * u + 1] = fmix_hi(sa[2 * u + 1], mw2, onef);
          qa[2 * u]     = fmix2_lo(qa[2 * u], m2, mw2);
          qa[2 * u + 1] = fmix2_hi(qa[2 * u + 1], m2, mw2);
        }
      }
    }
  }
  if (tail) {
    int sl = (cnn & ~3) + eg;
    int ex = __shfl(myE.x, sl);
    int ey = __shfl(myE.y, sl);
    bool act = eg < tail;
    int src = act ? (ex & 0x7fff) : 0;
    unsigned rr = act ? ((unsigned)ex >> 15) : 0u;
    float w = act ? __int_as_float(ey) : 0.f;
    int4 Hv = hin4[(unsigned)src * 16 + c8];
    int4 Rv = rel4[rr * 16 + c8];
    _Float16 wh = (_Float16)w;
    h2v w2 = {wh, wh};
    const h2v* hp = (const h2v*)&Hv;
    const h2v* rp = (const h2v*)&Rv;
    #pragma unroll
    for (int u = 0; u < 4; ++u) {
      h2v m2 = hp[u] * rp[u];
      h2v mw2 = m2 * w2;
      if (act) {
        mx2[u] = h2max(mx2[u], mw2);
        mn2[u] = h2min(mn2[u], mw2);
      }
      sa[2 * u]     = fmix_lo(sa[2 * u], mw2, onef);
      sa[2 * u + 1] = fmix_hi(sa[2 * u + 1], mw2, onef);
      qa[2 * u]     = fmix2_lo(qa[2 * u], m2, mw2);
      qa[2 * u + 1] = fmix2_hi(qa[2 * u + 1], m2, mw2);
    }
  }
  stats_finish(sa, qa, mx2, mn2, cnn, wid, eg, c8, (void*)&sh[0][0]);
  __syncthreads();
  if (tid < 64)
    mfma_epilogue<LAST>((const _Float16*)&sh[0][0], (const _Float16*)hin4, houth,
                        lg, logsum, Wm, bias, query, h_index, nbase, lane, false,
                        W1m, b1, W2, b2, out, hbuf);
}

extern "C" void kernel_launch(void* const* d_in, const int* in_sizes, int n_in,
                              void* d_out, int out_size, void* d_ws, size_t ws_size,
                              hipStream_t stream) {
  const int*   node_in  = (const int*)d_in[0];
  const int*   node_out = (const int*)d_in[1];
  const int*   relation = (const int*)d_in[2];
  const float* ew       = (const float*)d_in[3];
  const int*   h_index  = (const int*)d_in[4];
  const int*   r_index  = (const int*)d_in[5];
  const float* qemb     = (const float*)d_in[6];
  const float* relW     = (const float*)d_in[7];
  const float* relB     = (const float*)d_in[8];
  const float* linW     = (const float*)d_in[9];
  const float* linB     = (const float*)d_in[10];
  const float* W1       = (const float*)d_in[11];
  const float* b1       = (const float*)d_in[12];
  const float* W2       = (const float*)d_in[13];
  const float* b2       = (const float*)d_in[14];
  float* out = (float*)d_out;

  char* ws = (char*)d_ws;
  size_t off = 0;
  auto alloc = [&](size_t bytes) -> char* {
    char* p = ws + off;
    off += (bytes + 255) & ~(size_t)255;
    return p;
  };
  __half*   h0     = (__half*)  alloc((size_t)NN * BD * 2);
  __half*   h1buf  = (__half*)  alloc((size_t)NN * BD * 2);
  __half*   relIn  = (__half*)  alloc((size_t)LL * R2C * BD * 2);
  _Float16* Wm     = (_Float16*)alloc((size_t)LL * WMH * 2);
  _Float16* W1m    = (_Float16*)alloc((size_t)4096 * 2);
  int2*     ep     = (int2*)    alloc((size_t)NN * CAP * 8);
  int*      cnti   = (int*)     alloc((size_t)NN * 4);
  float*    stats  = (float*)   alloc(256);   // [0]=logsum (contiguous w/ cnti)
  float*    lg     = (float*)   alloc((size_t)NN * 4);
  float*    query  = (float*)   alloc((size_t)BD * 4);

  float* logsum = stats;

  // cnti and stats are contiguous (cnti padded to 256): one memset clears both
  hipMemsetAsync(cnti, 0, (((size_t)NN * 4 + 255) & ~(size_t)255) + 256, stream);

  build_setup_kernel<<<NEB + NWMB + NRELIN + NW1P + 1, 256, 0, stream>>>(
      node_in, node_out, relation, ew, cnti, ep,
      linW, Wm, r_index, qemb, relW, relB, relIn, query, W1, W1m);
  lg_kernel<<<98, 1024, 0, stream>>>(cnti, ep, lg, logsum);

  __half* hin = h0; __half* hout = h1buf;
  for (int l = 0; l < LL; ++l) {
    if (l == 0) {
      layer1_fused_kernel<<<NN / 4, 256, 0, stream>>>(
          (const int4*)relIn, ep, cnti, h_index, query, lg, logsum,
          Wm, linB, hout);
    } else if (l < LL - 1) {
      layer_fused_kernel<false><<<NN / 4, 256, 0, stream>>>(
          (const int4*)hin, (const int4*)relIn + (size_t)l * R2C * 16,
          ep, cnti, h_index, query, lg, logsum,
          Wm + (size_t)l * WMH, linB + (size_t)l * DD, hout,
          nullptr, nullptr, nullptr, nullptr, nullptr);
    } else {
      layer_fused_kernel<true><<<NN / 4, 256, 0, stream>>>(
          (const int4*)hin, (const int4*)relIn + (size_t)l * R2C * 16,
          ep, cnti, h_index, query, lg, logsum,
          Wm + (size_t)l * WMH, linB + (size_t)l * DD, hout,
          W1m, b1, W2, b2, out);
    }
    __half* tmp = hin; hin = hout; hout = tmp;
  }
}